// Round 1
// baseline (17.076 us; speedup 1.0000x reference)
//
#include <hip/hip_runtime.h>
#include <math.h>

// Only out[:, 0] is needed -> only the cls-token position matters.
// x, Wp, bp, A_log are provably unused. Output is identical across the
// 16 batches (cls token is broadcast).
//
// Pipeline (all f32):
//   xz   = cls @ W_in                    (256 -> 1024)
//   xh   = silu(xz[:512]*conv_w[:,3] + conv_b)   (causal conv at t=0: last tap only)
//   zs   = silu(xz[512:])
//   xdbl = xh @ W_x                      (512 -> 48)
//   delta= softplus(xdbl[:16] @ W_dt + b_dt)     (512)
//   s    = dot(xdbl[16:32], xdbl[32:48])         (scan at t=0 collapses: y0 = delta*xh*s)
//   y    = (xh*delta*s + xh*D_skip) * zs
//   out  = y @ W_out                     (512 -> 256), broadcast to 16 batches

#define NBLK 16
#define NTHR 512

__device__ __forceinline__ float siluf(float x) { return x / (1.0f + expf(-x)); }

__global__ __launch_bounds__(NTHR) void mamba_cls_kernel(
    const float* __restrict__ cls,      // (256,)
    const float* __restrict__ W_in,     // (256,1024)
    const float* __restrict__ conv_w,   // (512,4)
    const float* __restrict__ conv_b,   // (512,)
    const float* __restrict__ W_x,      // (512,48)
    const float* __restrict__ W_dt,     // (16,512)
    const float* __restrict__ b_dt,     // (512,)
    const float* __restrict__ D_skip,   // (512,)
    const float* __restrict__ W_out,    // (512,256)
    float* __restrict__ out,            // (16,256)
    float* __restrict__ ws)
{
    const int t = threadIdx.x;
    const int b = blockIdx.x;
    unsigned* ctr = (unsigned*)ws;          // zeroed via hipMemsetAsync each launch
    float* ws_xh = ws + 16;                 // 512 floats
    float* ws_zs = ws + 16 + 512;           // 512 floats

    __shared__ float cls_s[256];
    __shared__ float part1[8][64];
    __shared__ float xh_s[512];
    __shared__ float xdbl_part[8][48];
    __shared__ float xdbl[48];
    __shared__ float y_s[512];
    __shared__ float outpart[32][16];
    __shared__ float colsum[16];

    // ---------- Phase 1: xz columns [64b, 64b+64) = cls @ W_in ----------
    if (t < 256) cls_s[t] = cls[t];
    __syncthreads();
    {
        const int jl = t & 63;              // column within block
        const int chunk = t >> 6;           // 8 chunks x 32 rows
        const int j = b * 64 + jl;          // global column 0..1023
        const float* wcol = W_in + j;
        float acc = 0.f;
        #pragma unroll
        for (int r = 0; r < 32; ++r) {
            const int i = chunk * 32 + r;
            acc += cls_s[i] * wcol[i * 1024];
        }
        part1[chunk][jl] = acc;
    }
    __syncthreads();
    if (t < 64) {
        float v = 0.f;
        #pragma unroll
        for (int c = 0; c < 8; ++c) v += part1[c][t];
        const int j = b * 64 + t;
        if (j < 512) {
            // causal depthwise conv at t=0: only the last tap sees data
            const float pre = v * conv_w[j * 4 + 3] + conv_b[j];
            ws_xh[j] = siluf(pre);
        } else {
            ws_zs[j - 512] = siluf(v);
        }
    }

    // ---------- grid barrier (16 blocks, all co-resident) ----------
    __syncthreads();
    if (t == 0) {
        __threadfence();                    // agent-scope release of ws writes
        __hip_atomic_fetch_add(ctr, 1u, __ATOMIC_ACQ_REL, __HIP_MEMORY_SCOPE_AGENT);
        while (__hip_atomic_load(ctr, __ATOMIC_ACQUIRE, __HIP_MEMORY_SCOPE_AGENT)
               < (unsigned)NBLK) { }
    }
    __syncthreads();

    // ---------- Phase 2 (each block redundantly; tiny) ----------
    xh_s[t] = ws_xh[t];
    __syncthreads();

    // xdbl = xh @ W_x  (48 outputs) — wave w covers rows [64w, 64w+64)
    {
        const int w = t >> 6, lane = t & 63;
        if (lane < 48) {
            float acc = 0.f;
            for (int r = 0; r < 64; ++r) {
                const int i = w * 64 + r;
                acc += xh_s[i] * W_x[i * 48 + lane];
            }
            xdbl_part[w][lane] = acc;
        }
    }
    __syncthreads();
    if (t < 48) {
        float v = 0.f;
        #pragma unroll
        for (int c = 0; c < 8; ++c) v += xdbl_part[c][t];
        xdbl[t] = v;
    }
    __syncthreads();

    // delta, s, y (one element per thread)
    {
        float dtv = b_dt[t];
        #pragma unroll
        for (int r = 0; r < 16; ++r) dtv += xdbl[r] * W_dt[r * 512 + t];
        const float delta = (dtv > 20.f) ? dtv : log1pf(expf(dtv));   // softplus
        float s = 0.f;
        #pragma unroll
        for (int n = 0; n < 16; ++n) s += xdbl[16 + n] * xdbl[32 + n];
        const float xh_d = xh_s[t];
        y_s[t] = (xh_d * delta * s + xh_d * D_skip[t]) * ws_zs[t];
    }
    __syncthreads();

    // out columns [16b, 16b+16) = y @ W_out
    {
        const int cl = t & 15;
        const int chunk = t >> 4;           // 32 chunks x 16 rows
        const int c = b * 16 + cl;
        float acc = 0.f;
        #pragma unroll
        for (int r = 0; r < 16; ++r) {
            const int i = chunk * 16 + r;
            acc += y_s[i] * W_out[i * 256 + c];
        }
        outpart[chunk][cl] = acc;
    }
    __syncthreads();
    if (t < 16) {
        float v = 0.f;
        #pragma unroll
        for (int c = 0; c < 32; ++c) v += outpart[c][t];
        colsum[t] = v;
    }
    __syncthreads();
    if (t < 256) {
        const int batch = t >> 4;
        const int cl = t & 15;
        out[batch * 256 + b * 16 + cl] = colsum[cl];
    }
}

extern "C" void kernel_launch(void* const* d_in, const int* in_sizes, int n_in,
                              void* d_out, int out_size, void* d_ws, size_t ws_size,
                              hipStream_t stream) {
    // setup_inputs order:
    // 0 x, 1 cls_token, 2 Wp, 3 bp, 4 W_in, 5 conv_w, 6 conv_b,
    // 7 W_x, 8 W_dt, 9 b_dt, 10 A_log, 11 D_skip, 12 W_out
    const float* cls   = (const float*)d_in[1];
    const float* W_in  = (const float*)d_in[4];
    const float* convw = (const float*)d_in[5];
    const float* convb = (const float*)d_in[6];
    const float* W_x   = (const float*)d_in[7];
    const float* W_dt  = (const float*)d_in[8];
    const float* b_dt  = (const float*)d_in[9];
    const float* Dskip = (const float*)d_in[11];
    const float* W_out = (const float*)d_in[12];
    float* out = (float*)d_out;
    float* ws  = (float*)d_ws;

    // zero the grid-barrier counter every launch (ws is not re-poisoned
    // between graph replays, and we leave the counter at NBLK)
    hipMemsetAsync(d_ws, 0, 64, stream);
    mamba_cls_kernel<<<NBLK, NTHR, 0, stream>>>(cls, W_in, convw, convb, W_x,
                                                W_dt, b_dt, Dskip, W_out, out, ws);
}

// Round 2
// 14.270 us; speedup vs baseline: 1.1966x; 1.1966x over previous
//
#include <hip/hip_runtime.h>
#include <math.h>

// Only out[:, 0] is needed -> only the cls-token position matters.
// x, Wp, bp, A_log are provably unused; output rows are identical across batch.
//
// Pipeline (all f32):
//   xz   = cls @ W_in                          (256 -> 1024)
//   xh   = silu(xz[:512]*conv_w[:,3] + conv_b) (causal conv at t=0: last tap only)
//   zs   = silu(xz[512:])
//   xdbl = xh @ W_x                            (512 -> 48)
//   delta= softplus(xdbl[:16] @ W_dt + b_dt)   (512)
//   s    = dot(xdbl[16:32], xdbl[32:48])       (scan at t=0: y0 = delta*xh*s)
//   y    = (xh*delta*s + xh*D_skip) * zs
//   out  = y @ W_out                           (512 -> 256), broadcast to 16 batches
//
// Two kernels; the kernel boundary IS the grid sync (no atomic barrier, no memset).

#define NBLK1 32
#define NTHR1 256
#define NBLK2 32
#define NTHR2 512

__device__ __forceinline__ float siluf(float x) { return x / (1.0f + expf(-x)); }

// ---- k1: ws[0:512) = xh (post conv+silu), ws[512:1024) = zs = silu(z) ----
__global__ __launch_bounds__(NTHR1) void mamba_k1(
    const float* __restrict__ cls,      // (256,)
    const float* __restrict__ W_in,     // (256,1024)
    const float* __restrict__ conv_w,   // (512,4)
    const float* __restrict__ conv_b,   // (512,)
    float* __restrict__ ws)
{
    const int t = threadIdx.x;
    const int b = blockIdx.x;

    __shared__ float cls_s[256];
    __shared__ float part[8][32];

    cls_s[t] = cls[t];
    __syncthreads();

    // 32 columns per block, 8 threads per column (32 rows each)
    const int jl = t & 31;          // column within block
    const int r8 = t >> 5;          // row-chunk 0..7
    const int j  = b * 32 + jl;     // global column 0..1023
    float acc = 0.f;
    #pragma unroll
    for (int k = 0; k < 32; ++k) {
        const int i = r8 * 32 + k;
        acc += cls_s[i] * W_in[i * 1024 + j];
    }
    part[r8][jl] = acc;
    __syncthreads();

    if (t < 32) {
        float v = 0.f;
        #pragma unroll
        for (int c = 0; c < 8; ++c) v += part[c][t];
        const int jj = b * 32 + t;
        if (jj < 512) {
            // causal depthwise conv at t=0: only the last tap sees data
            ws[jj] = siluf(v * conv_w[jj * 4 + 3] + conv_b[jj]);
        } else {
            ws[jj] = siluf(v);   // zs
        }
    }
}

// ---- k2: xdbl -> delta,s -> y -> out columns [8b, 8b+8), all 16 batches ----
__global__ __launch_bounds__(NTHR2) void mamba_k2(
    const float* __restrict__ W_x,      // (512,48)
    const float* __restrict__ W_dt,     // (16,512)
    const float* __restrict__ b_dt,     // (512,)
    const float* __restrict__ D_skip,   // (512,)
    const float* __restrict__ W_out,    // (512,256)
    const float* __restrict__ ws,       // xh[512], zs[512]
    float* __restrict__ out)            // (16,256)
{
    const int t = threadIdx.x;
    const int b = blockIdx.x;

    __shared__ float xh_s[512];
    __shared__ float xdbl_part[8][48];
    __shared__ float xdbl[48];
    __shared__ float y_s[512];
    __shared__ float outpart[64][8];
    __shared__ float colsum[8];

    xh_s[t] = ws[t];
    __syncthreads();

    // xdbl = xh @ W_x (48 outputs); wave w covers rows [64w, 64w+64)
    {
        const int w = t >> 6, lane = t & 63;
        if (lane < 48) {
            float acc = 0.f;
            #pragma unroll
            for (int r = 0; r < 64; ++r) {
                const int i = w * 64 + r;
                acc += xh_s[i] * W_x[i * 48 + lane];
            }
            xdbl_part[w][lane] = acc;
        }
    }
    __syncthreads();
    if (t < 48) {
        float v = 0.f;
        #pragma unroll
        for (int c = 0; c < 8; ++c) v += xdbl_part[c][t];
        xdbl[t] = v;
    }
    __syncthreads();

    // delta, s, y (one element per thread)
    {
        float dtv = b_dt[t];
        #pragma unroll
        for (int r = 0; r < 16; ++r) dtv += xdbl[r] * W_dt[r * 512 + t];
        const float delta = (dtv > 20.f) ? dtv : log1pf(expf(dtv));   // softplus
        float s = 0.f;
        #pragma unroll
        for (int n = 0; n < 16; ++n) s += xdbl[16 + n] * xdbl[32 + n];
        const float xh_d = xh_s[t];
        y_s[t] = (xh_d * delta * s + xh_d * D_skip[t]) * ws[512 + t];
    }
    __syncthreads();

    // out columns [8b, 8b+8) = y @ W_out ; 64 row-chunks x 8 rows
    {
        const int cl = t & 7;
        const int chunk = t >> 3;
        const int c = b * 8 + cl;
        float acc = 0.f;
        #pragma unroll
        for (int r = 0; r < 8; ++r) {
            const int i = chunk * 8 + r;
            acc += y_s[i] * W_out[i * 256 + c];
        }
        outpart[chunk][cl] = acc;
    }
    __syncthreads();
    if (t < 8) {
        float v = 0.f;
        #pragma unroll
        for (int c = 0; c < 64; ++c) v += outpart[c][t];
        colsum[t] = v;
    }
    __syncthreads();
    if (t < 128) {
        const int batch = t >> 3;
        const int cl = t & 7;
        out[batch * 256 + b * 8 + cl] = colsum[cl];
    }
}

extern "C" void kernel_launch(void* const* d_in, const int* in_sizes, int n_in,
                              void* d_out, int out_size, void* d_ws, size_t ws_size,
                              hipStream_t stream) {
    // setup_inputs order:
    // 0 x, 1 cls_token, 2 Wp, 3 bp, 4 W_in, 5 conv_w, 6 conv_b,
    // 7 W_x, 8 W_dt, 9 b_dt, 10 A_log, 11 D_skip, 12 W_out
    const float* cls   = (const float*)d_in[1];
    const float* W_in  = (const float*)d_in[4];
    const float* convw = (const float*)d_in[5];
    const float* convb = (const float*)d_in[6];
    const float* W_x   = (const float*)d_in[7];
    const float* W_dt  = (const float*)d_in[8];
    const float* b_dt  = (const float*)d_in[9];
    const float* Dskip = (const float*)d_in[11];
    const float* W_out = (const float*)d_in[12];
    float* out = (float*)d_out;
    float* ws  = (float*)d_ws;

    mamba_k1<<<NBLK1, NTHR1, 0, stream>>>(cls, W_in, convw, convb, ws);
    mamba_k2<<<NBLK2, NTHR2, 0, stream>>>(W_x, W_dt, b_dt, Dskip, W_out, ws, out);
}